// Round 21
// baseline (48.258 us; speedup 1.0000x reference)
//
#include <hip/hip_runtime.h>
#include <hip/hip_bf16.h>
#include <stdint.h>

#define NR 16384
#define KI 256
#define MO 128
#define ALPHA 0.01f
#define CH 32             // rows per chunk (suffix pipeline)
#define NCH (NR / CH)     // 512 chunks
#define CK 512            // keys per sort-chunk
#define NCK (NR / CK)     // 32 sort-chunks
#define RB 4              // i's per thread in k_rank

typedef unsigned long long u64;
typedef __attribute__((ext_vector_type(8))) short bf16x8;
typedef __attribute__((ext_vector_type(4))) float f32x4;

// monotone float->u32 transform (order-preserving)
static __device__ __forceinline__ unsigned xf(float f) {
    unsigned u = __float_as_uint(f);
    return u ^ (((unsigned)((int)u >> 31)) | 0x80000000u);
}

static __device__ __forceinline__ ushort2 cvt2(float a, float b) {
    __hip_bfloat162 r = __float22bfloat162_rn(make_float2(a, b));
    return *reinterpret_cast<ushort2*>(&r);
}

// bf16 scalar pack/unpack (RNE; bit-exact unpack)
static __device__ __forceinline__ unsigned f2b(float f) {
    unsigned x = __float_as_uint(f);
    return (x + 0x7fffu + ((x >> 16) & 1u)) >> 16;
}
static __device__ __forceinline__ float b2f(unsigned u) {
    return __uint_as_float(u << 16);
}
static __device__ __forceinline__ unsigned pk(float hv, float sv) {
    return f2b(hv) | (f2b(sv) << 16);
}

// ---------------- K1: h(bf16) = x@W^T via bf16 MFMA, double-buffered LDS (1 barrier/K-step) ----------------
__global__ __launch_bounds__(256) void k_gemm_fused(const float* __restrict__ x,
                                                    const float* __restrict__ w,
                                                    const float* __restrict__ a1,
                                                    const float* __restrict__ a2,
                                                    ushort* __restrict__ hb,
                                                    float* __restrict__ s1,
                                                    float* __restrict__ s2,
                                                    unsigned* __restrict__ keys,
                                                    int* __restrict__ rank) {
    __shared__ ushort Abf[2][64][40];
    __shared__ ushort Bbf[2][128][40];
    const int t = threadIdx.x;
    const int lane = t & 63;
    const int wv = t >> 6;
    const int rowBase = blockIdx.x * 64;
    const int xr = t >> 2, xc = (t & 3) << 3;
    const int wr = t >> 1, wc = (t & 1) << 4;
    const int fr = lane & 15;
    const int fk = (lane >> 4) << 3;

    f32x4 acc[8] = {};

    float4 xv0 = *(const float4*)&x[(size_t)(rowBase + xr) * KI + xc];
    float4 xv1 = *(const float4*)&x[(size_t)(rowBase + xr) * KI + xc + 4];
    float4 wv0 = *(const float4*)&w[(size_t)wr * KI + wc];
    float4 wv1 = *(const float4*)&w[(size_t)wr * KI + wc + 4];
    float4 wv2 = *(const float4*)&w[(size_t)wr * KI + wc + 8];
    float4 wv3 = *(const float4*)&w[(size_t)wr * KI + wc + 12];

    int p = 0;
    for (int ks = 0; ks < KI / 32; ++ks) {
        // pack current tile regs -> buf[p]
        {
            union { ushort2 u2[4]; bf16x8 v; } ap;
            ap.u2[0] = cvt2(xv0.x, xv0.y); ap.u2[1] = cvt2(xv0.z, xv0.w);
            ap.u2[2] = cvt2(xv1.x, xv1.y); ap.u2[3] = cvt2(xv1.z, xv1.w);
            *(bf16x8*)&Abf[p][xr][xc] = ap.v;
            union { ushort2 u2[4]; bf16x8 v; } bp0, bp1;
            bp0.u2[0] = cvt2(wv0.x, wv0.y); bp0.u2[1] = cvt2(wv0.z, wv0.w);
            bp0.u2[2] = cvt2(wv1.x, wv1.y); bp0.u2[3] = cvt2(wv1.z, wv1.w);
            bp1.u2[0] = cvt2(wv2.x, wv2.y); bp1.u2[1] = cvt2(wv2.z, wv2.w);
            bp1.u2[2] = cvt2(wv3.x, wv3.y); bp1.u2[3] = cvt2(wv3.z, wv3.w);
            *(bf16x8*)&Bbf[p][wr][wc] = bp0.v;
            *(bf16x8*)&Bbf[p][wr][wc + 8] = bp1.v;
        }
        __syncthreads();   // writes to buf[p] visible; prior reads of buf[p^1] (step ks-1) already done
        if (ks + 1 < KI / 32) {   // prefetch next tile while MFMAing this one
            int k0 = (ks + 1) * 32;
            xv0 = *(const float4*)&x[(size_t)(rowBase + xr) * KI + k0 + xc];
            xv1 = *(const float4*)&x[(size_t)(rowBase + xr) * KI + k0 + xc + 4];
            wv0 = *(const float4*)&w[(size_t)wr * KI + k0 + wc];
            wv1 = *(const float4*)&w[(size_t)wr * KI + k0 + wc + 4];
            wv2 = *(const float4*)&w[(size_t)wr * KI + k0 + wc + 8];
            wv3 = *(const float4*)&w[(size_t)wr * KI + k0 + wc + 12];
        }
        bf16x8 af = *(const bf16x8*)&Abf[p][wv * 16 + fr][fk];
#pragma unroll
        for (int n = 0; n < 8; ++n) {
            bf16x8 bfr = *(const bf16x8*)&Bbf[p][n * 16 + fr][fk];
            acc[n] = __builtin_amdgcn_mfma_f32_16x16x32_bf16(af, bfr, acc[n], 0, 0, 0);
        }
        p ^= 1;
    }

    // epilogue: bf16 h-store. C/D: col = lane&15, row = (lane>>4)*4 + reg
    const int rq = lane >> 4;
#pragma unroll
    for (int n = 0; n < 8; ++n)
#pragma unroll
        for (int r = 0; r < 4; ++r)
            hb[(size_t)(rowBase + wv * 16 + rq * 4 + r) * MO + n * 16 + fr] = (ushort)f2b(acc[n][r]);

    float a1v[8], a2v[8];
#pragma unroll
    for (int n = 0; n < 8; ++n) { a1v[n] = a1[n * 16 + fr]; a2v[n] = a2[n * 16 + fr]; }
#pragma unroll
    for (int r = 0; r < 4; ++r) {
        float p1 = 0.f, p2 = 0.f;
#pragma unroll
        for (int n = 0; n < 8; ++n) {
            p1 = fmaf(acc[n][r], a1v[n], p1);
            p2 = fmaf(acc[n][r], a2v[n], p2);
        }
#pragma unroll
        for (int off = 8; off; off >>= 1) {
            p1 += __shfl_xor(p1, off, 64);
            p2 += __shfl_xor(p2, off, 64);
        }
        if (fr == 0) {
            int row = rowBase + wv * 16 + rq * 4 + r;
            s1[row] = p1;
            s2[row] = p2;
            keys[row] = (xf(p1) & 0xFFFFC000u) | (unsigned)row;
            rank[row] = 0;
        }
    }
}

// ---------------- K2: per-block chunk sort (redundant, parallel) + counting searches + atomic rank (R19) ----------------
__global__ __launch_bounds__(256) void k_rank(const unsigned* __restrict__ keys,
                                              int* __restrict__ rank) {
    __shared__ unsigned sc[CK];
    const int t = threadIdx.x;
    const int ibase = blockIdx.x * (256 * RB);
    const int cbase = blockIdx.y * CK;
    sc[t] = keys[cbase + t];
    sc[t + 256] = keys[cbase + 256 + t];
    unsigned ki[RB];
#pragma unroll
    for (int k = 0; k < RB; ++k) ki[k] = keys[ibase + k * 256 + t];
    __syncthreads();
    for (int k2 = 2; k2 <= CK; k2 <<= 1) {
        for (int j = k2 >> 1; j > 0; j >>= 1) {
            int i = ((t & ~(j - 1)) << 1) | (t & (j - 1));
            int p = i | j;
            bool up = ((i & k2) == 0);
            unsigned a = sc[i], b = sc[p];
            if ((a > b) == up) { sc[i] = b; sc[p] = a; }
            __syncthreads();
        }
    }
    int pos[RB] = {};
#pragma unroll
    for (int step = CK; step; step >>= 1) {
#pragma unroll
        for (int k = 0; k < RB; ++k) {
            int np = pos[k] + step;
            if (np <= CK && sc[np - 1] < ki[k]) pos[k] = np;
        }
    }
#pragma unroll
    for (int k = 0; k < RB; ++k)
        atomicAdd(&rank[ibase + k * 256 + t], pos[k]);   // int: deterministic
}

// ---------------- K3: scatter into sorted order (R16-identical) ----------------
__global__ __launch_bounds__(256) void k_scatter(const float* __restrict__ s1,
                                                 const int* __restrict__ rank,
                                                 float* __restrict__ s1s,
                                                 int* __restrict__ perm) {
    int i = blockIdx.x * 256 + threadIdx.x;
    int r = rank[i];
    s1s[r] = s1[i];
    perm[r] = i;
}

// ---------------- K4: within-chunk suffix + kidx on idle half-wave (R16-identical) ----------------
__global__ __launch_bounds__(256) void k_chunk(const ushort* __restrict__ hb,
                                               const int* __restrict__ perm,
                                               const float* __restrict__ s1s,
                                               const float* __restrict__ s2,
                                               unsigned* __restrict__ SHS,
                                               int* __restrict__ kidx) {
    __shared__ int pi[CH];
    __shared__ float ss[CH];
    __shared__ float rH[128], rS[128];
    const int t = threadIdx.x, c = t & 127, g = t >> 7, q = blockIdx.x;
    if (t < CH) { pi[t] = perm[q * CH + t]; ss[t] = s1s[q * CH + t]; }
    __syncthreads();
    float v[16];
#pragma unroll
    for (int m = 0; m < 16; ++m)
        v[m] = b2f(hb[(size_t)pi[g * 16 + m] * MO + c]);
    if (g == 1) {
        float runH = 0.f, runS = 0.f;
#pragma unroll
        for (int m = 15; m >= 0; --m) {
            runH += v[m];
            runS = fmaf(ss[16 + m], v[m], runS);
            SHS[(size_t)(q * CH + 16 + m) * MO + c] = pk(runH, runS);
        }
        rH[c] = runH; rS[c] = runS;
    } else if (t < CH) {
        int i = q * CH + t;
        unsigned qtv = xf(-s2[i]) & 0xFFFFC000u;
        int lo = 0, hi = NR;
        while (lo < hi) {
            int mid = (lo + hi) >> 1;
            if ((xf(s1s[mid]) & 0xFFFFC000u) < qtv) lo = mid + 1; else hi = mid;
        }
        kidx[i] = lo;
    }
    __syncthreads();
    if (g == 0) {
        float runH = rH[c], runS = rS[c];
#pragma unroll
        for (int m = 15; m >= 0; --m) {
            runH += v[m];
            runS = fmaf(ss[m], v[m], runS);
            SHS[(size_t)(q * CH + m) * MO + c] = pk(runH, runS);
        }
    }
    if (q == NCH - 1 && t < 128) SHS[(size_t)NR * MO + t] = 0u;
}

// ---------------- K5: exclusive suffix over chunk sums (R16-identical) ----------------
__global__ __launch_bounds__(512) void k_scan(const unsigned* __restrict__ SHS,
                                              float2* __restrict__ cSuf) {
    __shared__ float bufH[NCH], bufS[NCH];
    const int c = blockIdx.x, q = threadIdx.x;
    unsigned hu = SHS[(size_t)(q * CH) * MO + c];
    float vh = b2f(hu & 0xffffu), vs = b2f(hu >> 16);
    bufH[q] = vh; bufS[q] = vs;
    __syncthreads();
#pragma unroll
    for (int off = 1; off < NCH; off <<= 1) {
        float ah = 0.f, as = 0.f;
        if (q + off < NCH) { ah = bufH[q + off]; as = bufS[q + off]; }
        __syncthreads();
        bufH[q] += ah; bufS[q] += as;
        __syncthreads();
    }
    cSuf[q * MO + c] = make_float2(bufH[q] - vh, bufS[q] - vs);
    if (q == 0) cSuf[(size_t)NCH * MO + c] = make_float2(0.f, 0.f);
}

// ---------------- K6: out[i][c]; SH = unpack(SHS[k]) + cSuf[k>>5] (R16-identical) ----------------
__global__ __launch_bounds__(256) void k_final(const unsigned* __restrict__ SHS,
                                               const float2* __restrict__ cSuf,
                                               const float* __restrict__ s2,
                                               const int* __restrict__ kidx,
                                               float* __restrict__ out) {
    int idx = blockIdx.x * 256 + threadIdx.x;
    int i = idx >> 7, c = idx & 127;
    float s2v = s2[i];
    int k = kidx[i];
    unsigned w0u = SHS[c];
    float2 c0 = cSuf[c];
    unsigned wku = SHS[(size_t)k * MO + c];
    float2 ck = cSuf[(size_t)(k >> 5) * MO + c];
    float th  = b2f(w0u & 0xffffu) + c0.x, tsh  = b2f(w0u >> 16) + c0.y;
    float sh  = b2f(wku & 0xffffu) + ck.x, sshv = b2f(wku >> 16) + ck.y;
    out[idx] = ALPHA * fmaf(s2v, th, tsh) + (1.f - ALPHA) * fmaf(s2v, sh, sshv);
}

extern "C" void kernel_launch(void* const* d_in, const int* in_sizes, int n_in,
                              void* d_out, int out_size, void* d_ws, size_t ws_size,
                              hipStream_t stream) {
    const float* x  = (const float*)d_in[0];
    const float* w  = (const float*)d_in[1];
    const float* a1 = (const float*)d_in[2];
    const float* a2 = (const float*)d_in[3];
    float* out = (float*)d_out;

    char* ws = (char*)d_ws;
    ushort*   hb   = (ushort*)ws;                                       // NR*MO bf16 (4 MB)
    unsigned* SHS  = (unsigned*)(ws + (size_t)NR * MO * 2);             // (NR+1)*MO packed bf16x2 (8.4 MB)
    float2*   cSuf = (float2*)((char*)SHS + (size_t)(NR + 1) * MO * 4); // (NCH+1)*MO float2
    float*    s1   = (float*)((char*)cSuf + (size_t)(NCH + 1) * MO * 8);
    float*    s2   = s1 + NR;
    float*    s1s  = s2 + NR;
    unsigned* keys = (unsigned*)(s1s + NR);                             // NR u32
    int*      perm = (int*)(keys + NR);                                 // NR
    int*      kidx = perm + NR;                                         // NR
    int*      rank = kidx + NR;                                         // NR

    k_gemm_fused<<<NR / 64, 256, 0, stream>>>(x, w, a1, a2, hb, s1, s2, keys, rank);
    k_rank<<<dim3(NR / (256 * RB), NCK), 256, 0, stream>>>(keys, rank);
    k_scatter<<<NR / 256, 256, 0, stream>>>(s1, rank, s1s, perm);
    k_chunk<<<NCH, 256, 0, stream>>>(hb, perm, s1s, s2, SHS, kidx);
    k_scan<<<MO, NCH, 0, stream>>>(SHS, cSuf);
    k_final<<<(NR * MO) / 256, 256, 0, stream>>>(SHS, cSuf, s2, kidx, out);
}

// Round 22
// 45.138 us; speedup vs baseline: 1.0691x; 1.0691x over previous
//
#include <hip/hip_runtime.h>
#include <hip/hip_bf16.h>
#include <stdint.h>

#define NR 16384
#define KI 256
#define MO 128
#define ALPHA 0.01f
#define CH 32             // rows per chunk (suffix pipeline)
#define NCH (NR / CH)     // 512 chunks
#define CK 512            // keys per sort-chunk
#define NCK (NR / CK)     // 32 sort-chunks
#define RB 4              // i's per thread in k_rank

typedef unsigned long long u64;
typedef __attribute__((ext_vector_type(8))) short bf16x8;
typedef __attribute__((ext_vector_type(4))) float f32x4;

// monotone float->u32 transform (order-preserving)
static __device__ __forceinline__ unsigned xf(float f) {
    unsigned u = __float_as_uint(f);
    return u ^ (((unsigned)((int)u >> 31)) | 0x80000000u);
}

static __device__ __forceinline__ ushort2 cvt2(float a, float b) {
    __hip_bfloat162 r = __float22bfloat162_rn(make_float2(a, b));
    return *reinterpret_cast<ushort2*>(&r);
}

// bf16 scalar pack/unpack (RNE; bit-exact unpack)
static __device__ __forceinline__ unsigned f2b(float f) {
    unsigned x = __float_as_uint(f);
    return (x + 0x7fffu + ((x >> 16) & 1u)) >> 16;
}
static __device__ __forceinline__ float b2f(unsigned u) {
    return __uint_as_float(u << 16);
}
static __device__ __forceinline__ unsigned pk(float hv, float sv) {
    return f2b(hv) | (f2b(sv) << 16);
}

// ---------------- K1: h(bf16) = x@W^T via bf16 MFMA + fused s1,s2,key32, rank=0 (R19-identical) ----------------
__global__ __launch_bounds__(256) void k_gemm_fused(const float* __restrict__ x,
                                                    const float* __restrict__ w,
                                                    const float* __restrict__ a1,
                                                    const float* __restrict__ a2,
                                                    ushort* __restrict__ hb,
                                                    float* __restrict__ s1,
                                                    float* __restrict__ s2,
                                                    unsigned* __restrict__ keys,
                                                    int* __restrict__ rank) {
    __shared__ ushort Abf[64][40];
    __shared__ ushort Bbf[128][40];
    const int t = threadIdx.x;
    const int lane = t & 63;
    const int wv = t >> 6;
    const int rowBase = blockIdx.x * 64;
    const int xr = t >> 2, xc = (t & 3) << 3;
    const int wr = t >> 1, wc = (t & 1) << 4;
    const int fr = lane & 15;
    const int fk = (lane >> 4) << 3;

    f32x4 acc[8] = {};

    float4 xv0 = *(const float4*)&x[(size_t)(rowBase + xr) * KI + xc];
    float4 xv1 = *(const float4*)&x[(size_t)(rowBase + xr) * KI + xc + 4];
    float4 wv0 = *(const float4*)&w[(size_t)wr * KI + wc];
    float4 wv1 = *(const float4*)&w[(size_t)wr * KI + wc + 4];
    float4 wv2 = *(const float4*)&w[(size_t)wr * KI + wc + 8];
    float4 wv3 = *(const float4*)&w[(size_t)wr * KI + wc + 12];

    for (int ks = 0; ks < KI / 32; ++ks) {
        __syncthreads();
        {
            union { ushort2 u2[4]; bf16x8 v; } ap;
            ap.u2[0] = cvt2(xv0.x, xv0.y); ap.u2[1] = cvt2(xv0.z, xv0.w);
            ap.u2[2] = cvt2(xv1.x, xv1.y); ap.u2[3] = cvt2(xv1.z, xv1.w);
            *(bf16x8*)&Abf[xr][xc] = ap.v;
            union { ushort2 u2[4]; bf16x8 v; } bp0, bp1;
            bp0.u2[0] = cvt2(wv0.x, wv0.y); bp0.u2[1] = cvt2(wv0.z, wv0.w);
            bp0.u2[2] = cvt2(wv1.x, wv1.y); bp0.u2[3] = cvt2(wv1.z, wv1.w);
            bp1.u2[0] = cvt2(wv2.x, wv2.y); bp1.u2[1] = cvt2(wv2.z, wv2.w);
            bp1.u2[2] = cvt2(wv3.x, wv3.y); bp1.u2[3] = cvt2(wv3.z, wv3.w);
            *(bf16x8*)&Bbf[wr][wc] = bp0.v;
            *(bf16x8*)&Bbf[wr][wc + 8] = bp1.v;
        }
        __syncthreads();
        if (ks + 1 < KI / 32) {
            int k0 = (ks + 1) * 32;
            xv0 = *(const float4*)&x[(size_t)(rowBase + xr) * KI + k0 + xc];
            xv1 = *(const float4*)&x[(size_t)(rowBase + xr) * KI + k0 + xc + 4];
            wv0 = *(const float4*)&w[(size_t)wr * KI + k0 + wc];
            wv1 = *(const float4*)&w[(size_t)wr * KI + k0 + wc + 4];
            wv2 = *(const float4*)&w[(size_t)wr * KI + k0 + wc + 8];
            wv3 = *(const float4*)&w[(size_t)wr * KI + k0 + wc + 12];
        }
        bf16x8 af = *(const bf16x8*)&Abf[wv * 16 + fr][fk];
#pragma unroll
        for (int n = 0; n < 8; ++n) {
            bf16x8 bfr = *(const bf16x8*)&Bbf[n * 16 + fr][fk];
            acc[n] = __builtin_amdgcn_mfma_f32_16x16x32_bf16(af, bfr, acc[n], 0, 0, 0);
        }
    }

    const int rq = lane >> 4;
#pragma unroll
    for (int n = 0; n < 8; ++n)
#pragma unroll
        for (int r = 0; r < 4; ++r)
            hb[(size_t)(rowBase + wv * 16 + rq * 4 + r) * MO + n * 16 + fr] = (ushort)f2b(acc[n][r]);

    float a1v[8], a2v[8];
#pragma unroll
    for (int n = 0; n < 8; ++n) { a1v[n] = a1[n * 16 + fr]; a2v[n] = a2[n * 16 + fr]; }
#pragma unroll
    for (int r = 0; r < 4; ++r) {
        float p1 = 0.f, p2 = 0.f;
#pragma unroll
        for (int n = 0; n < 8; ++n) {
            p1 = fmaf(acc[n][r], a1v[n], p1);
            p2 = fmaf(acc[n][r], a2v[n], p2);
        }
#pragma unroll
        for (int off = 8; off; off >>= 1) {
            p1 += __shfl_xor(p1, off, 64);
            p2 += __shfl_xor(p2, off, 64);
        }
        if (fr == 0) {
            int row = rowBase + wv * 16 + rq * 4 + r;
            s1[row] = p1;
            s2[row] = p2;
            keys[row] = (xf(p1) & 0xFFFFC000u) | (unsigned)row;
            rank[row] = 0;
        }
    }
}

// ---------------- K2: per-block chunk sort (redundant, parallel) + counting searches + atomic rank (R19) ----------------
__global__ __launch_bounds__(256) void k_rank(const unsigned* __restrict__ keys,
                                              int* __restrict__ rank) {
    __shared__ unsigned sc[CK];
    const int t = threadIdx.x;
    const int ibase = blockIdx.x * (256 * RB);
    const int cbase = blockIdx.y * CK;
    sc[t] = keys[cbase + t];
    sc[t + 256] = keys[cbase + 256 + t];
    unsigned ki[RB];
#pragma unroll
    for (int k = 0; k < RB; ++k) ki[k] = keys[ibase + k * 256 + t];
    __syncthreads();
    for (int k2 = 2; k2 <= CK; k2 <<= 1) {
        for (int j = k2 >> 1; j > 0; j >>= 1) {
            int i = ((t & ~(j - 1)) << 1) | (t & (j - 1));
            int p = i | j;
            bool up = ((i & k2) == 0);
            unsigned a = sc[i], b = sc[p];
            if ((a > b) == up) { sc[i] = b; sc[p] = a; }
            __syncthreads();
        }
    }
    int pos[RB] = {};
#pragma unroll
    for (int step = CK; step; step >>= 1) {
#pragma unroll
        for (int k = 0; k < RB; ++k) {
            int np = pos[k] + step;
            if (np <= CK && sc[np - 1] < ki[k]) pos[k] = np;
        }
    }
#pragma unroll
    for (int k = 0; k < RB; ++k)
        atomicAdd(&rank[ibase + k * 256 + t], pos[k]);   // int: deterministic
}

// ---------------- K3: scatter into sorted order (R16-identical) ----------------
__global__ __launch_bounds__(256) void k_scatter(const float* __restrict__ s1,
                                                 const int* __restrict__ rank,
                                                 float* __restrict__ s1s,
                                                 int* __restrict__ perm) {
    int i = blockIdx.x * 256 + threadIdx.x;
    int r = rank[i];
    s1s[r] = s1[i];
    perm[r] = i;
}

// ---------------- K4: within-chunk suffix + kidx on idle half-wave (R16-identical) ----------------
__global__ __launch_bounds__(256) void k_chunk(const ushort* __restrict__ hb,
                                               const int* __restrict__ perm,
                                               const float* __restrict__ s1s,
                                               const float* __restrict__ s2,
                                               unsigned* __restrict__ SHS,
                                               int* __restrict__ kidx) {
    __shared__ int pi[CH];
    __shared__ float ss[CH];
    __shared__ float rH[128], rS[128];
    const int t = threadIdx.x, c = t & 127, g = t >> 7, q = blockIdx.x;
    if (t < CH) { pi[t] = perm[q * CH + t]; ss[t] = s1s[q * CH + t]; }
    __syncthreads();
    float v[16];
#pragma unroll
    for (int m = 0; m < 16; ++m)
        v[m] = b2f(hb[(size_t)pi[g * 16 + m] * MO + c]);
    if (g == 1) {
        float runH = 0.f, runS = 0.f;
#pragma unroll
        for (int m = 15; m >= 0; --m) {
            runH += v[m];
            runS = fmaf(ss[16 + m], v[m], runS);
            SHS[(size_t)(q * CH + 16 + m) * MO + c] = pk(runH, runS);
        }
        rH[c] = runH; rS[c] = runS;
    } else if (t < CH) {
        int i = q * CH + t;
        unsigned qtv = xf(-s2[i]) & 0xFFFFC000u;
        int lo = 0, hi = NR;
        while (lo < hi) {
            int mid = (lo + hi) >> 1;
            if ((xf(s1s[mid]) & 0xFFFFC000u) < qtv) lo = mid + 1; else hi = mid;
        }
        kidx[i] = lo;
    }
    __syncthreads();
    if (g == 0) {
        float runH = rH[c], runS = rS[c];
#pragma unroll
        for (int m = 15; m >= 0; --m) {
            runH += v[m];
            runS = fmaf(ss[m], v[m], runS);
            SHS[(size_t)(q * CH + m) * MO + c] = pk(runH, runS);
        }
    }
    if (q == NCH - 1 && t < 128) SHS[(size_t)NR * MO + t] = 0u;
}

// ---------------- K5: exclusive suffix over chunk sums (R16-identical) ----------------
__global__ __launch_bounds__(512) void k_scan(const unsigned* __restrict__ SHS,
                                              float2* __restrict__ cSuf) {
    __shared__ float bufH[NCH], bufS[NCH];
    const int c = blockIdx.x, q = threadIdx.x;
    unsigned hu = SHS[(size_t)(q * CH) * MO + c];
    float vh = b2f(hu & 0xffffu), vs = b2f(hu >> 16);
    bufH[q] = vh; bufS[q] = vs;
    __syncthreads();
#pragma unroll
    for (int off = 1; off < NCH; off <<= 1) {
        float ah = 0.f, as = 0.f;
        if (q + off < NCH) { ah = bufH[q + off]; as = bufS[q + off]; }
        __syncthreads();
        bufH[q] += ah; bufS[q] += as;
        __syncthreads();
    }
    cSuf[q * MO + c] = make_float2(bufH[q] - vh, bufS[q] - vs);
    if (q == 0) cSuf[(size_t)NCH * MO + c] = make_float2(0.f, 0.f);
}

// ---------------- K6: out[i][c]; SH = unpack(SHS[k]) + cSuf[k>>5] (R16-identical) ----------------
__global__ __launch_bounds__(256) void k_final(const unsigned* __restrict__ SHS,
                                               const float2* __restrict__ cSuf,
                                               const float* __restrict__ s2,
                                               const int* __restrict__ kidx,
                                               float* __restrict__ out) {
    int idx = blockIdx.x * 256 + threadIdx.x;
    int i = idx >> 7, c = idx & 127;
    float s2v = s2[i];
    int k = kidx[i];
    unsigned w0u = SHS[c];
    float2 c0 = cSuf[c];
    unsigned wku = SHS[(size_t)k * MO + c];
    float2 ck = cSuf[(size_t)(k >> 5) * MO + c];
    float th  = b2f(w0u & 0xffffu) + c0.x, tsh  = b2f(w0u >> 16) + c0.y;
    float sh  = b2f(wku & 0xffffu) + ck.x, sshv = b2f(wku >> 16) + ck.y;
    out[idx] = ALPHA * fmaf(s2v, th, tsh) + (1.f - ALPHA) * fmaf(s2v, sh, sshv);
}

extern "C" void kernel_launch(void* const* d_in, const int* in_sizes, int n_in,
                              void* d_out, int out_size, void* d_ws, size_t ws_size,
                              hipStream_t stream) {
    const float* x  = (const float*)d_in[0];
    const float* w  = (const float*)d_in[1];
    const float* a1 = (const float*)d_in[2];
    const float* a2 = (const float*)d_in[3];
    float* out = (float*)d_out;

    char* ws = (char*)d_ws;
    ushort*   hb   = (ushort*)ws;                                       // NR*MO bf16 (4 MB)
    unsigned* SHS  = (unsigned*)(ws + (size_t)NR * MO * 2);             // (NR+1)*MO packed bf16x2 (8.4 MB)
    float2*   cSuf = (float2*)((char*)SHS + (size_t)(NR + 1) * MO * 4); // (NCH+1)*MO float2
    float*    s1   = (float*)((char*)cSuf + (size_t)(NCH + 1) * MO * 8);
    float*    s2   = s1 + NR;
    float*    s1s  = s2 + NR;
    unsigned* keys = (unsigned*)(s1s + NR);                             // NR u32
    int*      perm = (int*)(keys + NR);                                 // NR
    int*      kidx = perm + NR;                                         // NR
    int*      rank = kidx + NR;                                         // NR

    k_gemm_fused<<<NR / 64, 256, 0, stream>>>(x, w, a1, a2, hb, s1, s2, keys, rank);
    k_rank<<<dim3(NR / (256 * RB), NCK), 256, 0, stream>>>(keys, rank);
    k_scatter<<<NR / 256, 256, 0, stream>>>(s1, rank, s1s, perm);
    k_chunk<<<NCH, 256, 0, stream>>>(hb, perm, s1s, s2, SHS, kidx);
    k_scan<<<MO, NCH, 0, stream>>>(SHS, cSuf);
    k_final<<<(NR * MO) / 256, 256, 0, stream>>>(SHS, cSuf, s2, kidx, out);
}